// Round 11
// baseline (577.883 us; speedup 1.0000x reference)
//
#include <hip/hip_runtime.h>

#define BB    256
#define NIN   1152
#define OO    10
#define IL    8
#define OL    16
#define ROW   160
#define EPSQ  1e-7f
#define NCH   144
#define NPN   8      // n per chunk
#define BTILE 64

// One routing pass; u_hat recomputed on the fly, w/x read STRAIGHT FROM L2
// (w = 5.9 MB, L2-resident across all blocks; round-10's LDS staging caused
// 5.9M bank-conflict cycles + 2 blocks/CU occupancy and is gone entirely).
// Grid (BB/64, 144). Block 256 thr = 64 groups of 4 lanes; group g owns
// b = b0+g for the chunk's 8 n's. Lane q owns row-chunks c = q+4j, j=0..4
// (8 floats each of the 160-float [o][k] row; o = c>>1 = 2j+(q>>1),
// h = c&1 = q&1, so elem offset = c*8 and w offset = (q>>1)*128+(q&1)*8
// + j*256 + i*16 — per-lane base + compile-time immediates).
// Epilogue = round-8/10's verified 4-lane softmax (shfl_xor(1)/(2), width 4).
template<int ITER>
__global__ __launch_bounds__(256) void caps_pass(
    const float* __restrict__ x, const float* __restrict__ w,
    const float* __restrict__ vin, float* __restrict__ partial)
{
    const int t  = threadIdx.x;
    const int q  = t & 3;
    const int g  = t >> 2;              // 0..63 = b within tile
    const int b  = blockIdx.x * BTILE + g;
    const int nc = blockIdx.y;
    const int n0 = nc * NPN;

    // per-lane w base for this chunk-set: o-parity + k-half offset
    const float* wq = w + (size_t)n0 * 1280 + ((q >> 1) * 128 + (q & 1) * 8);
    const float* xq = x + ((size_t)b * NIN + n0) * 8;

    float vs[5][8];
    if (ITER) {
        #pragma unroll
        for (int j = 0; j < 5; ++j) {
            const float* vp = vin + (size_t)b * ROW + (q + 4 * j) * 8;
            const float4 a  = *reinterpret_cast<const float4*>(vp);
            const float4 c4 = *reinterpret_cast<const float4*>(vp + 4);
            vs[j][0] = a.x;  vs[j][1] = a.y;  vs[j][2] = a.z;  vs[j][3] = a.w;
            vs[j][4] = c4.x; vs[j][5] = c4.y; vs[j][6] = c4.z; vs[j][7] = c4.w;
        }
    }

    float sp[5][8];
    #pragma unroll
    for (int j = 0; j < 5; ++j)
        #pragma unroll
        for (int e = 0; e < 8; ++e) sp[j][e] = 0.f;

    for (int nn = 0; nn < NPN; ++nn) {
        float xr[8];
        {
            const float4 x0 = *reinterpret_cast<const float4*>(xq + nn * 8);
            const float4 x1 = *reinterpret_cast<const float4*>(xq + nn * 8 + 4);
            xr[0] = x0.x; xr[1] = x0.y; xr[2] = x0.z; xr[3] = x0.w;
            xr[4] = x1.x; xr[5] = x1.y; xr[6] = x1.z; xr[7] = x1.w;
        }
        const float* wn = wq + (size_t)nn * 1280;

        float acc[5][8];
        #pragma unroll
        for (int j = 0; j < 5; ++j) {
            #pragma unroll
            for (int e = 0; e < 8; ++e) acc[j][e] = 0.f;
            #pragma unroll
            for (int i = 0; i < IL; ++i) {
                const float4 wlo = *reinterpret_cast<const float4*>(wn + j * 256 + i * 16);
                const float4 whi = *reinterpret_cast<const float4*>(wn + j * 256 + i * 16 + 4);
                acc[j][0] = fmaf(wlo.x, xr[i], acc[j][0]);
                acc[j][1] = fmaf(wlo.y, xr[i], acc[j][1]);
                acc[j][2] = fmaf(wlo.z, xr[i], acc[j][2]);
                acc[j][3] = fmaf(wlo.w, xr[i], acc[j][3]);
                acc[j][4] = fmaf(whi.x, xr[i], acc[j][4]);
                acc[j][5] = fmaf(whi.y, xr[i], acc[j][5]);
                acc[j][6] = fmaf(whi.z, xr[i], acc[j][6]);
                acc[j][7] = fmaf(whi.w, xr[i], acc[j][7]);
            }
        }

        if (ITER == 0) {
            #pragma unroll
            for (int j = 0; j < 5; ++j)
                #pragma unroll
                for (int e = 0; e < 8; ++e) sp[j][e] += acc[j][e];
        } else {
            float d[5], dd[5];
            #pragma unroll
            for (int j = 0; j < 5; ++j) {
                float a = acc[j][0] * vs[j][0];
                #pragma unroll
                for (int e = 1; e < 8; ++e) a = fmaf(acc[j][e], vs[j][e], a);
                a += __shfl_xor(a, 1, 4);      // combine halves -> full 16-k dot
                d[j] = a;
            }
            #pragma unroll
            for (int j = 0; j < 5; ++j) dd[j] = __shfl_xor(d[j], 2, 4);

            float mx = fmaxf(d[0], dd[0]);
            #pragma unroll
            for (int j = 1; j < 5; ++j) mx = fmaxf(mx, fmaxf(d[j], dd[j]));
            float e_[5], se = 0.f;
            #pragma unroll
            for (int j = 0; j < 5; ++j) {
                e_[j] = __expf(d[j] - mx);
                se += e_[j] + __expf(dd[j] - mx);
            }
            const float rinv = 1.f / se;
            #pragma unroll
            for (int j = 0; j < 5; ++j) {
                const float c = e_[j] * rinv;
                #pragma unroll
                for (int e = 0; e < 8; ++e)
                    sp[j][e] = fmaf(c, acc[j][e], sp[j][e]);
            }
        }
    }

    // each (b, chunk) owned by exactly one group: direct partial write
    #pragma unroll
    for (int j = 0; j < 5; ++j) {
        float* pp = partial + ((size_t)nc * BB + b) * ROW + (q + 4 * j) * 8;
        *reinterpret_cast<float4*>(pp) =
            make_float4(sp[j][0], sp[j][1], sp[j][2], sp[j][3]);
        *reinterpret_cast<float4*>(pp + 4) =
            make_float4(sp[j][4], sp[j][5], sp[j][6], sp[j][7]);
    }
}

// Sum partials over chunks + bias, squash; optional prevAdd (running v-sum).
__global__ __launch_bounds__(192) void caps_reduce(
    const float* __restrict__ partial, const float* __restrict__ bias,
    const float* __restrict__ prevAdd, float* __restrict__ outv, float scale)
{
    const int t = threadIdx.x;
    if (t >= ROW) return;
    const int b = blockIdx.x;

    float s0 = 0.f, s1 = 0.f, s2 = 0.f, s3 = 0.f;
    const float* p = partial + (size_t)b * ROW + t;
    for (int ch = 0; ch < NCH; ch += 4) {
        s0 += p[(size_t)(ch + 0) * BB * ROW];
        s1 += p[(size_t)(ch + 1) * BB * ROW];
        s2 += p[(size_t)(ch + 2) * BB * ROW];
        s3 += p[(size_t)(ch + 3) * BB * ROW];
    }
    float s = scale * ((s0 + s1) + (s2 + s3)) + bias[t];

    float d = s * s;
    d += __shfl_xor(d, 1, 16);
    d += __shfl_xor(d, 2, 16);
    d += __shfl_xor(d, 4, 16);
    d += __shfl_xor(d, 8, 16);
    const float f = d / ((1.f + d) * sqrtf(d + EPSQ));
    float v = f * s;
    if (prevAdd) v += prevAdd[(size_t)b * ROW + t];
    outv[(size_t)b * ROW + t] = v;
}

extern "C" void kernel_launch(void* const* d_in, const int* in_sizes, int n_in,
                              void* d_out, int out_size, void* d_ws, size_t ws_size,
                              hipStream_t stream) {
    const float* x    = (const float*)d_in[0]; // (B, NIN, 8, 1)
    const float* w    = (const float*)d_in[1]; // (1, NIN, O, 8, 16)
    const float* bias = (const float*)d_in[2]; // (1, 1, O, 16, 1)
    float* out = (float*)d_out;                // (B, 1, O, 16, 1)

    float* partial = (float*)d_ws;                       // 144*256*160 f32
    float* v0  = partial + (size_t)NCH * BB * ROW;
    float* vsb = v0 + (size_t)BB * ROW;

    const dim3 pg(BB / BTILE, NCH);

    // iter0: uniform c (scale 0.1) -> v0
    caps_pass<0><<<pg, 256, 0, stream>>>(x, w, nullptr, partial);
    caps_reduce<<<BB, 192, 0, stream>>>(partial, bias, nullptr, v0, 0.1f);
    // iter1: c = softmax(u.v0) -> vsb = v0 + v1
    caps_pass<1><<<pg, 256, 0, stream>>>(x, w, v0, partial);
    caps_reduce<<<BB, 192, 0, stream>>>(partial, bias, v0, vsb, 1.0f);
    // iter2: c = softmax(u.(v0+v1)) -> out
    caps_pass<2><<<pg, 256, 0, stream>>>(x, w, vsb, partial);
    caps_reduce<<<BB, 192, 0, stream>>>(partial, bias, nullptr, out, 1.0f);
}

// Round 12
// 120.720 us; speedup vs baseline: 4.7870x; 4.7870x over previous
//
#include <hip/hip_runtime.h>
#include <hip/hip_bf16.h>

#define BB   256
#define NIN  1152
#define OO   10
#define IL   8
#define OL   16
#define ROW  (OO*OL)      // 160
#define EPSQ 1e-7f
#define NT   8            // n-tile per build block
#define BT   32           // b-tile per build block

typedef unsigned short ushx8 __attribute__((ext_vector_type(8)));
typedef unsigned short ushx4 __attribute__((ext_vector_type(4)));

__device__ __forceinline__ float bf2f(unsigned short h) {
    unsigned u = ((unsigned)h) << 16;
    return __builtin_bit_cast(float, u);
}

// K1: build u_hat[b][n][o*16+k] in bf16. (verified, round 8)
__global__ __launch_bounds__(160) void caps_build(
    const float* __restrict__ x, const float* __restrict__ w,
    unsigned short* __restrict__ u)
{
    __shared__ float4 wl4[NT][321];     // 320 float4 per n + 1 pad
    __shared__ float4 xl4[BT * 16];     // [bl][nl*2+h]
    const int t  = threadIdx.x;
    const int n0 = blockIdx.x * NT;
    const int b0 = blockIdx.y * BT;

    // stage w (o-parity swizzle -> conflict-free), coalesced global reads
    const float4* wg = reinterpret_cast<const float4*>(w) + (size_t)n0 * 320;
    for (int j = t; j < NT * 320; j += 160) {
        const int row = j / 320;
        const int lin = j - row * 320;
        const int o   = lin >> 5;
        const int rem = lin & 31;
        const int i   = rem >> 2;
        const int kh  = rem & 3;
        const int ip  = i ^ (o & 1);
        wl4[row][(o << 5) | (ip << 2) | kh] = wg[j];
    }
    // stage x (linear, coalesced)
    const float4* xg = reinterpret_cast<const float4*>(x);
    for (int j = t; j < BT * 16; j += 160) {
        const int bl = j >> 4;
        const int r  = j & 15;
        xl4[j] = xg[((size_t)(b0 + bl) * NIN + n0) * 2 + r];
    }
    __syncthreads();

    const int nl = t / 20;
    const int s  = t - nl * 20;
    const int o  = s >> 1;
    const int k8 = s & 1;
    const int p  = o & 1;
    const float4* wbase = &wl4[nl][(o << 5) | (k8 << 1)];
    const float4* xbase = &xl4[nl * 2];
    unsigned short* ub = u + ((size_t)b0 * NIN + n0 + nl) * ROW + o * OL + k8 * 8;
    const size_t ustride = (size_t)NIN * ROW;

    for (int bl = 0; bl < BT; bl += 4) {
        float xv[4][IL];
        #pragma unroll
        for (int bb = 0; bb < 4; ++bb) {
            const float4 x0 = xbase[(bl + bb) * 16];
            const float4 x1 = xbase[(bl + bb) * 16 + 1];
            xv[bb][0] = x0.x; xv[bb][1] = x0.y; xv[bb][2] = x0.z; xv[bb][3] = x0.w;
            xv[bb][4] = x1.x; xv[bb][5] = x1.y; xv[bb][6] = x1.z; xv[bb][7] = x1.w;
        }

        float acc[4][8];
        #pragma unroll
        for (int bb = 0; bb < 4; ++bb)
            #pragma unroll
            for (int j = 0; j < 8; ++j) acc[bb][j] = 0.f;

        #pragma unroll
        for (int i = 0; i < IL; ++i) {
            const float4 wlo = wbase[(i ^ p) << 2];
            const float4 whi = wbase[((i ^ p) << 2) | 1];
            const float wv[8] = {wlo.x, wlo.y, wlo.z, wlo.w, whi.x, whi.y, whi.z, whi.w};
            #pragma unroll
            for (int bb = 0; bb < 4; ++bb)
                #pragma unroll
                for (int j = 0; j < 8; ++j)
                    acc[bb][j] = fmaf(wv[j], xv[bb][i], acc[bb][j]);
        }

        #pragma unroll
        for (int bb = 0; bb < 4; ++bb) {
            union { ushx8 v; __hip_bfloat162 h[4]; } pk;
            #pragma unroll
            for (int j = 0; j < 4; ++j)
                pk.h[j] = __float22bfloat162_rn(make_float2(acc[bb][2*j], acc[bb][2*j+1]));
            *reinterpret_cast<ushx8*>(ub + (size_t)(bl + bb) * ustride) = pk.v;
        }
    }
}

// K2: all 3 routing iterations fused, one block per b. 1024 thr = 16 waves =
// 256 4-lane groups (round 8 had 768/12 waves -> 29% occupancy, the sweep
// limiter). n-split is uneven but wave-uniform: groups g<128 do 5 steps
// (n = g+256m, m=0..4), groups g>=128 do 4 (covers [0,1152) exactly once).
// Lane q of a group owns row chunks {q+4j} (16B = 8 bf16 of one o).
__global__ __launch_bounds__(1024) void caps_route3(
    const unsigned short* __restrict__ u, const float* __restrict__ bias,
    float* __restrict__ outv)
{
    __shared__ float lds[16][ROW];
    __shared__ float vbuf[ROW];
    const int t  = threadIdx.x;
    const int q  = t & 3;
    const int g  = t >> 2;     // 0..255
    const int wv = t >> 6;     // 0..15
    const int b  = blockIdx.x;
    const int msteps = (g < 128) ? 5 : 4;   // wave-uniform
    const unsigned short* ub = u + (size_t)b * NIN * ROW;

    float bsv = 0.f;
    if (t < ROW) bsv = bias[t];
    float vprev = 0.f;

    #pragma unroll
    for (int iter = 0; iter < 3; ++iter) {
        float sp[5][8];
        #pragma unroll
        for (int j = 0; j < 5; ++j)
            #pragma unroll
            for (int e = 0; e < 8; ++e) sp[j][e] = 0.f;

        if (iter == 0) {
            for (int m = 0; m < msteps; ++m) {
                const unsigned short* un = ub + (size_t)(g + m * 256) * ROW;
                #pragma unroll
                for (int j = 0; j < 5; ++j) {
                    const ushx8 raw = *reinterpret_cast<const ushx8*>(un + (q + 4 * j) * 8);
                    #pragma unroll
                    for (int e = 0; e < 8; ++e) sp[j][e] += bf2f(raw[e]);
                }
            }
        } else {
            float vs[5][8];
            #pragma unroll
            for (int j = 0; j < 5; ++j) {
                #pragma unroll
                for (int e = 0; e < 8; ++e) vs[j][e] = vbuf[(q + 4 * j) * 8 + e];
            }

            for (int m = 0; m < msteps; ++m) {
                const unsigned short* un = ub + (size_t)(g + m * 256) * ROW;
                float uf[5][8];
                #pragma unroll
                for (int j = 0; j < 5; ++j) {
                    const ushx8 raw = *reinterpret_cast<const ushx8*>(un + (q + 4 * j) * 8);
                    #pragma unroll
                    for (int e = 0; e < 8; ++e) uf[j][e] = bf2f(raw[e]);
                }

                // own-parity dots (half-k), combine halves, then swap parity
                float d[5], dd[5];
                #pragma unroll
                for (int j = 0; j < 5; ++j) {
                    float acc = uf[j][0] * vs[j][0];
                    #pragma unroll
                    for (int e = 1; e < 8; ++e) acc = fmaf(uf[j][e], vs[j][e], acc);
                    acc += __shfl_xor(acc, 1, 4);   // h=0 + h=1 -> full 16-k dot
                    d[j] = acc;
                }
                #pragma unroll
                for (int j = 0; j < 5; ++j) dd[j] = __shfl_xor(d[j], 2, 4);

                float mx = fmaxf(d[0], dd[0]);
                #pragma unroll
                for (int j = 1; j < 5; ++j) mx = fmaxf(mx, fmaxf(d[j], dd[j]));
                float se = 0.f, e_[5];
                #pragma unroll
                for (int j = 0; j < 5; ++j) {
                    e_[j] = __expf(d[j] - mx);
                    se += e_[j] + __expf(dd[j] - mx);
                }
                const float r = 1.f / se;
                #pragma unroll
                for (int j = 0; j < 5; ++j) {
                    const float c = e_[j] * r;
                    #pragma unroll
                    for (int e = 0; e < 8; ++e)
                        sp[j][e] = fmaf(c, uf[j][e], sp[j][e]);
                }
            }
        }

        // butterfly over the 16 groups of each wave (masks preserve q)
        #pragma unroll
        for (int j = 0; j < 5; ++j)
            #pragma unroll
            for (int e = 0; e < 8; ++e) {
                #pragma unroll
                for (int msk = 4; msk <= 32; msk <<= 1)
                    sp[j][e] += __shfl_xor(sp[j][e], msk);
            }
        if ((t & 63) < 4) {
            #pragma unroll
            for (int j = 0; j < 5; ++j)
                #pragma unroll
                for (int e = 0; e < 8; ++e)
                    lds[wv][(q + 4 * j) * 8 + e] = sp[j][e];
        }
        __syncthreads();

        if (t < ROW) {
            float ssum = 0.f;
            #pragma unroll
            for (int wvi = 0; wvi < 16; ++wvi) ssum += lds[wvi][t];
            const float sv = (iter == 0 ? 0.1f : 1.0f) * ssum + bsv;

            float dq = sv * sv;
            dq += __shfl_xor(dq, 1, 16);
            dq += __shfl_xor(dq, 2, 16);
            dq += __shfl_xor(dq, 4, 16);
            dq += __shfl_xor(dq, 8, 16);
            const float f = dq / ((1.f + dq) * sqrtf(dq + EPSQ));
            const float v = f * sv;

            if (iter == 0) { vbuf[t] = v; vprev = v; }
            else if (iter == 1) { vbuf[t] = v + vprev; }
            else { outv[(size_t)b * ROW + t] = v; }
        }
        __syncthreads();
    }
}

extern "C" void kernel_launch(void* const* d_in, const int* in_sizes, int n_in,
                              void* d_out, int out_size, void* d_ws, size_t ws_size,
                              hipStream_t stream) {
    const float* x    = (const float*)d_in[0]; // (B, NIN, 8, 1)
    const float* w    = (const float*)d_in[1]; // (1, NIN, O, 8, 16)
    const float* bias = (const float*)d_in[2]; // (1, 1, O, 16, 1)
    float* out = (float*)d_out;                // (B, 1, O, 16, 1)

    unsigned short* u = (unsigned short*)d_ws; // BB*NIN*ROW bf16 = 94.4 MB

    caps_build<<<dim3(NIN / NT, BB / BT), 160, 0, stream>>>(x, w, u);
    caps_route3<<<BB, 1024, 0, stream>>>(u, bias, out);
}